// Round 12
// baseline (240.327 us; speedup 1.0000x reference)
//
#include <hip/hip_runtime.h>
#include <stdint.h>

#define B_ 8
#define C_ 256
#define N_ 4096

typedef __attribute__((ext_vector_type(8))) short short8;
typedef __attribute__((ext_vector_type(4))) float float4v;
typedef __attribute__((ext_vector_type(16))) float floatx16;

__device__ __forceinline__ uint16_t f2bfr(float f) {
  return (uint16_t)((__float_as_uint(f) + 0x8000u) >> 16);
}
__device__ __forceinline__ uint32_t pkbf(float lo, float hi) {
  return ((__float_as_uint(hi) + 0x8000u) & 0xffff0000u) |
         ((__float_as_uint(lo) + 0x8000u) >> 16);
}
// 2^x via compiler builtin -> single v_exp_f32 with correct trans-op hazard
// handling (inline-asm version raced the hazard window -> NaN, R9/R10).
__device__ __forceinline__ float ex2(float x) {
  return __builtin_amdgcn_exp2f(x);
}
// 16B LDS read as 2x b64 (rows 152B-strided: dw-stride 38 == 6 mod 32,
// gcd(6,32)=2 -> 2-way bank aliasing == free per m136.)
__device__ __forceinline__ short8 ld8(const uint16_t* p) {
  union { ushort4 h[2]; short8 v; } u;
  u.h[0] = *reinterpret_cast<const ushort4*>(p);
  u.h[1] = *reinterpret_cast<const ushort4*>(p + 4);
  return u.v;
}

// ---------------------------------------------------------------------------
// Kernel 0: W fp32 -> Wc bf16, biases fp32. Wq/bq pre-scaled by log2(e) so
// attn's softmax uses exp2 directly (R11-validated).
// ---------------------------------------------------------------------------
__global__ __launch_bounds__(256) void wconv_kernel(
    const float* __restrict__ Wq, const float* __restrict__ bq,
    const float* __restrict__ Wk, const float* __restrict__ bk,
    const float* __restrict__ Wv, const float* __restrict__ bv,
    uint16_t* __restrict__ Wc, float* __restrict__ bc)
{
  const float L2E = 1.44269504088896f;
  int tg = blockIdx.x * 256 + threadIdx.x;
  int idx = tg * 4;
  const float* src = (idx < 8192) ? (Wq + idx)
                   : (idx < 16384) ? (Wk + (idx - 8192))
                                   : (Wv + (idx - 16384));
  float sc = (idx < 8192) ? L2E : 1.0f;
  float4 wv = *reinterpret_cast<const float4*>(src);
  uint2 o;
  o.x = pkbf(wv.x * sc, wv.y * sc);
  o.y = pkbf(wv.z * sc, wv.w * sc);
  *reinterpret_cast<uint2*>(Wc + idx) = o;
  if (tg < 320)
    bc[tg] = (tg < 32) ? bq[tg] * L2E : (tg < 64) ? bk[tg - 32] : bv[tg - 64];
}

// ---------------------------------------------------------------------------
// Kernel 1: QKV via MFMA. 1-D grid, XCD-pinned (b = blockIdx.x & 7).
// V epilogue shuffle-merges D-fragments across the 4-lane n-group so each
// lane stores ONE dwordx2 (R8-validated: total -3us vs 2B scattered stores).
// ---------------------------------------------------------------------------
__global__ __launch_bounds__(512, 4) void qkv_mfma(
    const float* __restrict__ x, const uint16_t* __restrict__ Wc,
    const float* __restrict__ bc,
    uint16_t* __restrict__ Qw, uint16_t* __restrict__ Kw, uint16_t* __restrict__ Vw)
{
  __shared__ __align__(16) uint16_t xs[64][268];
  const int b = blockIdx.x & 7;         // XCD pin
  const int tile = blockIdx.x >> 3;
  const int n0 = tile * 64;
  const int tid = threadIdx.x;
  const int nl = tid & 63, grp = tid >> 6;
  const int w = grp, l15 = tid & 15, q = (tid & 63) >> 4;
  const int nb = w & 3;

  const float* xb = x + (size_t)b * C_ * N_ + n0;
  #pragma unroll
  for (int it = 0; it < 16; ++it) {
    int c2 = it * 16 + grp * 2;
    float f0 = xb[(size_t)c2 * N_ + nl];
    float f1 = xb[(size_t)(c2 + 1) * N_ + nl];
    *reinterpret_cast<uint32_t*>(&xs[nl][c2]) = pkbf(f0, f1);
  }
  __syncthreads();

  float4v acc[10];
  #pragma unroll
  for (int i = 0; i < 10; ++i) acc[i] = (float4v){0.f, 0.f, 0.f, 0.f};

  const int ob0 = (w >> 2) * 10;
  #pragma unroll
  for (int h2 = 0; h2 < 2; ++h2) {
    short8 bx[4];
    #pragma unroll
    for (int kb = 0; kb < 4; ++kb)
      bx[kb] = ld8(&xs[nb * 16 + l15][h2 * 128 + kb * 32 + q * 8]);
    #pragma unroll
    for (int oi = 0; oi < 10; ++oi) {
      int ob = ob0 + oi;
      const uint16_t* wr = Wc + (size_t)(ob * 16 + l15) * 256 + h2 * 128 + q * 8;
      short8 aw[4];
      #pragma unroll
      for (int kb = 0; kb < 4; ++kb)
        aw[kb] = *reinterpret_cast<const short8*>(wr + kb * 32);
      #pragma unroll
      for (int kb = 0; kb < 4; ++kb)
        acc[oi] = __builtin_amdgcn_mfma_f32_16x16x32_bf16(aw[kb], bx[kb], acc[oi], 0, 0, 0);
    }
  }

  // ---- Q/K epilogue (ob 0..3 live in waves 0-3) via LDS transpose ----
  __syncthreads();
  uint16_t (*qs)[72] = reinterpret_cast<uint16_t(*)[72]>(&xs[0][0]);
  if (w < 4) {
    #pragma unroll
    for (int oi = 0; oi < 4; ++oi) {
      float4v a = acc[oi];
      const float* bb = bc + oi * 16 + q * 4;
      uint2 pk2;
      pk2.x = pkbf(a.x + bb[0], a.y + bb[1]);
      pk2.y = pkbf(a.z + bb[2], a.w + bb[3]);
      *reinterpret_cast<uint2*>(&qs[nb * 16 + l15][oi * 16 + q * 4]) = pk2;
    }
  }
  __syncthreads();
  if (tid < 256) {
    int n = tid >> 2, sub = tid & 3;
    const uint16_t* row = qs[n];
    uint4 d0 = *reinterpret_cast<const uint4*>(&row[sub * 16]);
    uint4 d1 = *reinterpret_cast<const uint4*>(&row[sub * 16 + 8]);
    size_t nn = (size_t)b * N_ + n0 + n;
    if (sub < 2) {
      uint4* dst = reinterpret_cast<uint4*>(Qw + nn * 32 + sub * 16);
      dst[0] = d0; dst[1] = d1;
    } else {
      uint4* dst = reinterpret_cast<uint4*>(Kw + nn * 32 + (sub - 2) * 16);
      dst[0] = d0; dst[1] = d1;
    }
  }
  // ---- V epilogue into swizzled layout, shuffle-merged 8B stores ----
  const size_t blk = ((size_t)b * 64 + tile) * 4;
  const int half = l15 >> 3;
  const int podd = l15 & 1, s2 = (l15 >> 1) & 1;
  const int nq = (l15 & 7) & ~3;                 // n-quad base within 8
  #pragma unroll
  for (int oi = 0; oi < 10; ++oi) {
    int ob = ob0 + oi;
    if (ob < 4) continue;
    float4v a = acc[oi];
    const float* bb = bc + ob * 16 + q * 4;
    int cb = ob * 16 - 64 + q * 4;
    float v0 = a.x + bb[0], v1 = a.y + bb[1];
    float v2 = a.z + bb[2], v3 = a.w + bb[3];
    float t0 = __shfl_xor(v0, 1), t1 = __shfl_xor(v1, 1);
    float t2 = __shfl_xor(v2, 1), t3 = __shfl_xor(v3, 1);
    uint32_t wA = podd ? pkbf(t2, v2) : pkbf(v0, t0);
    uint32_t wB = podd ? pkbf(t3, v3) : pkbf(v1, t1);
    uint32_t uA = __shfl_xor(wA, 2), uB = __shfl_xor(wB, 2);
    uint2 st;
    int cfin;
    if (!s2) { st.x = wA; st.y = uA; cfin = cb + 2 * podd; }
    else     { st.x = uB; st.y = wB; cfin = cb + 2 * podd + 1; }
    size_t vaddr = (blk + (cfin >> 6)) * 4096
                 + (size_t)(nb * 1024 + ((cfin >> 5) & 1) * 512 + half * 256
                            + (cfin & 31) * 8 + nq);
    *reinterpret_cast<uint2*>(Vw + vaddr) = st;
  }
}

// ---------------------------------------------------------------------------
// Kernel 2: MFMA flash attention. Round-12: M-tile 64 -> 32 rows, grid 1024,
// 4 blocks/CU (was grid-capped at 2 -> 50% occupancy; measured 36%).
// Rationale: R4/R6/R11 exonerated conflicts, barrier count, VALU work —
// the stall is aligned latency chains in an 8-wave lockstep with only one
// partner block. Halving per-block work doubles independent barrier groups
// per CU (TLP). Aggregate MFMA/SIMD unchanged. Cost: 2x K/V L2 reads
// (288MB/XCD, ~67us floor at 4.3TB/s per-XCD L2 -> still below target).
// VGPR budget: single O accumulator (-16) fits __launch_bounds__(512,8).
// Schedule per-iteration is the 3x-validated R4 structure, halved.
// ---------------------------------------------------------------------------
__global__ __launch_bounds__(512, 8) void attn_mfma(
    const uint16_t* __restrict__ Qw, const uint16_t* __restrict__ Kw,
    const uint16_t* __restrict__ Vw, const float* __restrict__ x,
    const float* __restrict__ gamma, float* __restrict__ out)
{
  __shared__ __align__(16) union Smem {
    uint16_t Ps[2][32 * 76];      // 9728 B, rows 152B (38 dw == 6 mod 32)
    float Os[128 * 33];           // 16896 B, stride 33 == 1 mod 32
  } sm;
  __shared__ float Ls[32];

  const int b = blockIdx.x & 7;         // XCD pin (matches qkv)
  const int m0 = (blockIdx.x >> 3) * 32;
  const int tid = threadIdx.x;
  const int w = tid >> 6, lane = tid & 63;
  const int l15 = lane & 15, q = lane >> 4;
  const int l31 = lane & 31, half = lane >> 5;
  const int nb = w & 3, mbp = w >> 2;   // S: wave covers m-block mbp, keys nb

  const uint16_t* Kb = Kw + (size_t)b * N_ * 32 + (size_t)(nb * 16 + l15) * 32 + q * 8;
  const short8 qf = *reinterpret_cast<const short8*>(
      Qw + ((size_t)b * N_ + m0 + mbp * 16 + l15) * 32 + q * 8);
  // swizzled V: lane offset within (b, tile, cg) 4096-elem block
  const uint16_t* Vb = Vw + ((size_t)b * 256 + (w >> 1)) * 4096
                     + (w & 1) * 512 + half * 256 + l31 * 8;

  floatx16 O;
  #pragma unroll
  for (int i = 0; i < 16; ++i) O[i] = 0.f;
  float rs = 0.f;
  const float4v zero4 = (float4v){0.f, 0.f, 0.f, 0.f};
  if (tid < 32) Ls[tid] = 0.f;

  // ---- prolog: S[0] -> Ps[0]; preload vc = V(0), kc = K(1) ----
  short8 vc[4];
  #pragma unroll
  for (int ks = 0; ks < 4; ++ks)
    vc[ks] = *reinterpret_cast<const short8*>(Vb + ks * 1024);
  short8 kc = *reinterpret_cast<const short8*>(Kb + (size_t)64 * 32);
  {
    short8 kf = *reinterpret_cast<const short8*>(Kb);
    float4v s0 = __builtin_amdgcn_mfma_f32_16x16x32_bf16(kf, qf, zero4, 0, 0, 0);
    float p0 = ex2(s0.x), p1 = ex2(s0.y), p2 = ex2(s0.z), p3 = ex2(s0.w);
    rs += (p0 + p1) + (p2 + p3);
    uint2 pw; pw.x = pkbf(p0, p1); pw.y = pkbf(p2, p3);
    *reinterpret_cast<uint2*>(&sm.Ps[0][(mbp * 16 + l15) * 76 + nb * 16 + q * 4]) = pw;
  }
  __syncthreads();

  for (int t = 0; t < 64; ++t) {
    const int buf = t & 1;

    // issue NEXT-iter loads (consumed next iteration -> full-iter latency cover)
    short8 vn[4];
    if (t < 63) {
      const uint16_t* vt = Vb + (size_t)(t + 1) * 16384;
      #pragma unroll
      for (int ks = 0; ks < 4; ++ks)
        vn[ks] = *reinterpret_cast<const short8*>(vt + ks * 1024);
    }
    short8 kn;
    if (t < 62)
      kn = *reinterpret_cast<const short8*>(Kb + (size_t)(t + 2) * 64 * 32);

    // ---- S[t+1] -> Ps[buf^1] (kc loaded last iter, already in registers) ----
    if (t < 63) {
      float4v s0 = __builtin_amdgcn_mfma_f32_16x16x32_bf16(kc, qf, zero4, 0, 0, 0);
      float p0 = ex2(s0.x), p1 = ex2(s0.y), p2 = ex2(s0.z), p3 = ex2(s0.w);
      rs += (p0 + p1) + (p2 + p3);
      uint2 pw; pw.x = pkbf(p0, p1); pw.y = pkbf(p2, p3);
      *reinterpret_cast<uint2*>(&sm.Ps[buf ^ 1][(mbp * 16 + l15) * 76 + nb * 16 + q * 4]) = pw;
    }

    // ---- PV[t]: A = Ps[buf] via 2xb64 (32 rows), B = vc (registers) ----
    #pragma unroll
    for (int ks = 0; ks < 4; ++ks) {
      short8 pa = ld8(&sm.Ps[buf][l31 * 76 + ks * 16 + half * 8]);
      O = __builtin_amdgcn_mfma_f32_32x32x16_bf16(pa, vc[ks], O, 0, 0, 0);
    }
    __syncthreads();

    // rotate register prefetch buffers
    if (t < 63) {
      #pragma unroll
      for (int ks = 0; ks < 4; ++ks) vc[ks] = vn[ks];
    }
    if (t < 62) kc = kn;
  }

  // ---- row sums -> Ls = gamma / rowsum ----
  rs += __shfl_xor(rs, 16); rs += __shfl_xor(rs, 32);
  if (q == 0) atomicAdd(&Ls[mbp * 16 + l15], rs);
  __syncthreads();
  if (tid < 32) Ls[tid] = gamma[0] / Ls[tid];
  __syncthreads();   // Ls ready; all Ps reads done -> Os may overwrite

  // ---- epilogue: O (32x32 D layout) -> Os transpose -> coalesced stores ----
  #pragma unroll
  for (int chunk = 0; chunk < 2; ++chunk) {
    if ((w >> 2) == chunk) {
      int cl = (w & 3) * 32 + l31;
      #pragma unroll
      for (int reg = 0; reg < 16; ++reg) {
        int m = (reg & 3) + 8 * (reg >> 2) + 4 * half;
        sm.Os[cl * 33 + m] = O[reg] * Ls[m];
      }
    }
    __syncthreads();
    {
      int cl = tid >> 2, msub = tid & 3;
      int c = chunk * 128 + cl;
      size_t idx = ((size_t)b * C_ + c) * N_ + m0 + msub * 8;
      const float* os = &sm.Os[cl * 33 + msub * 8];
      #pragma unroll
      for (int i = 0; i < 2; ++i) {
        float4 xv = *reinterpret_cast<const float4*>(x + idx + i * 4);
        float4 ov;
        ov.x = os[i * 4 + 0] + xv.x;
        ov.y = os[i * 4 + 1] + xv.y;
        ov.z = os[i * 4 + 2] + xv.z;
        ov.w = os[i * 4 + 3] + xv.w;
        *reinterpret_cast<float4*>(out + idx + i * 4) = ov;
      }
    }
    __syncthreads();
  }
}

extern "C" void kernel_launch(void* const* d_in, const int* in_sizes, int n_in,
                              void* d_out, int out_size, void* d_ws, size_t ws_size,
                              hipStream_t stream) {
  const float* x     = (const float*)d_in[0];
  const float* Wq    = (const float*)d_in[1];
  const float* bq    = (const float*)d_in[2];
  const float* Wk    = (const float*)d_in[3];
  const float* bk    = (const float*)d_in[4];
  const float* Wv    = (const float*)d_in[5];
  const float* bv    = (const float*)d_in[6];
  const float* gamma = (const float*)d_in[7];
  float* out = (float*)d_out;

  // ws: Qw bf16 2MB | Kw bf16 2MB | Vw bf16 16MB (swizzled) | Wc | bc
  uint16_t* Qw = (uint16_t*)d_ws;
  uint16_t* Kw = Qw + (size_t)B_ * N_ * 32;
  uint16_t* Vw = Kw + (size_t)B_ * N_ * 32;
  uint16_t* Wc = Vw + (size_t)B_ * C_ * N_;
  float*    bc = (float*)(Wc + 320 * 256);

  wconv_kernel<<<80, 256, 0, stream>>>(Wq, bq, Wk, bk, Wv, bv, Wc, bc);
  qkv_mfma<<<512, 512, 0, stream>>>(x, Wc, bc, Qw, Kw, Vw);
  attn_mfma<<<1024, 512, 0, stream>>>(Qw, Kw, Vw, x, gamma, out);
}

// Round 13
// 202.609 us; speedup vs baseline: 1.1862x; 1.1862x over previous
//
#include <hip/hip_runtime.h>
#include <stdint.h>

#define B_ 8
#define C_ 256
#define N_ 4096

typedef __attribute__((ext_vector_type(8))) short short8;
typedef __attribute__((ext_vector_type(4))) float float4v;
typedef __attribute__((ext_vector_type(16))) float floatx16;

__device__ __forceinline__ uint16_t f2bfr(float f) {
  return (uint16_t)((__float_as_uint(f) + 0x8000u) >> 16);
}
__device__ __forceinline__ uint32_t pkbf(float lo, float hi) {
  return ((__float_as_uint(hi) + 0x8000u) & 0xffff0000u) |
         ((__float_as_uint(lo) + 0x8000u) >> 16);
}
// 2^x via compiler builtin -> single v_exp_f32 with correct trans-op hazard
// handling (inline-asm version raced the hazard window -> NaN, R9/R10).
__device__ __forceinline__ float ex2(float x) {
  return __builtin_amdgcn_exp2f(x);
}
// 16B LDS read as 2x b64 (rows with dw-stride == 2 or 6 mod 32 -> 2-way
// bank aliasing == free per m136).
__device__ __forceinline__ short8 ld8(const uint16_t* p) {
  union { ushort4 h[2]; short8 v; } u;
  u.h[0] = *reinterpret_cast<const ushort4*>(p);
  u.h[1] = *reinterpret_cast<const ushort4*>(p + 4);
  return u.v;
}

// ---------------------------------------------------------------------------
// Kernel 0: W fp32 -> Wc bf16, biases fp32. Wq/bq pre-scaled by log2(e) so
// attn's softmax uses exp2 directly (R11-validated).
// ---------------------------------------------------------------------------
__global__ __launch_bounds__(256) void wconv_kernel(
    const float* __restrict__ Wq, const float* __restrict__ bq,
    const float* __restrict__ Wk, const float* __restrict__ bk,
    const float* __restrict__ Wv, const float* __restrict__ bv,
    uint16_t* __restrict__ Wc, float* __restrict__ bc)
{
  const float L2E = 1.44269504088896f;
  int tg = blockIdx.x * 256 + threadIdx.x;
  int idx = tg * 4;
  const float* src = (idx < 8192) ? (Wq + idx)
                   : (idx < 16384) ? (Wk + (idx - 8192))
                                   : (Wv + (idx - 16384));
  float sc = (idx < 8192) ? L2E : 1.0f;
  float4 wv = *reinterpret_cast<const float4*>(src);
  uint2 o;
  o.x = pkbf(wv.x * sc, wv.y * sc);
  o.y = pkbf(wv.z * sc, wv.w * sc);
  *reinterpret_cast<uint2*>(Wc + idx) = o;
  if (tg < 320)
    bc[tg] = (tg < 32) ? bq[tg] * L2E : (tg < 64) ? bk[tg - 32] : bv[tg - 64];
}

// ---------------------------------------------------------------------------
// Kernel 1: QKV via 32x32x16 MFMA (round-13 rewrite). Rationale: qkv is the
// invisible ~90us of the 225 total (attn measured 97.5; wconv+gaps ~30) at a
// ~15-20us roofline. Old 16x16x32 loop: 80 L2 Wc loads/wave consumed
// immediately (latency-exposed), 640KB/block A-traffic. 32x32x16 has 2x the
// FLOP per A-byte; A-frag shared across the two n-tiles; Q/K tiles reuse the
// V path's B-frags -> A-traffic 640->192KB/block, A-loads 80->16-32/wave.
// Operand layouts copied from attn's VERIFIED PV mfma (A: row=l31,
// k=half*8+j; B: col=l31; D: col=l31, row=(reg&3)+8*(reg>>2)+4*half).
// V epilogue: D -> vs LDS [256][68] (stride 34dw == 2 mod 32, free) ->
// 4x coalesced dwordx4 stores per thread into the swizzled Vw layout.
// ---------------------------------------------------------------------------
__global__ __launch_bounds__(512, 4) void qkv_mfma(
    const float* __restrict__ x, const uint16_t* __restrict__ Wc,
    const float* __restrict__ bc,
    uint16_t* __restrict__ Qw, uint16_t* __restrict__ Kw, uint16_t* __restrict__ Vw)
{
  __shared__ __align__(16) union Smem {
    uint16_t xs[64][268];                 // 34304 B staging (MFMA phase)
    struct {
      uint16_t qs[64][72];                // 9216 B  (epilogue)
      uint16_t vs[256][68];               // 34816 B (epilogue)
    } e;
  } sm;

  const int b = blockIdx.x & 7;           // XCD pin
  const int tile = blockIdx.x >> 3;
  const int n0 = tile * 64;
  const int tid = threadIdx.x;
  const int nl = tid & 63, grp = tid >> 6;
  const int w = grp, lane = tid & 63;
  const int l31 = lane & 31, half = lane >> 5;

  // ---- stage x tile (bf16-packed, [n][c]) ----
  const float* xb = x + (size_t)b * C_ * N_ + n0;
  #pragma unroll
  for (int it = 0; it < 16; ++it) {
    int c2 = it * 16 + grp * 2;
    float f0 = xb[(size_t)c2 * N_ + nl];
    float f1 = xb[(size_t)(c2 + 1) * N_ + nl];
    *reinterpret_cast<uint32_t*>(&sm.xs[nl][c2]) = pkbf(f0, f1);
  }
  __syncthreads();

  // ---- MFMA phase: wave w owns V c-tile (rows 64+w*32..+31) x both n-tiles;
  //      waves 0-3 additionally own one Q/K tile (qct=w>>1, qnt=w&1). ----
  floatx16 accV0, accV1, accQ;
  #pragma unroll
  for (int i = 0; i < 16; ++i) { accV0[i] = 0.f; accV1[i] = 0.f; accQ[i] = 0.f; }

  const uint16_t* wrV = Wc + (size_t)(64 + w * 32 + l31) * 256 + half * 8;
  const int qct = w >> 1, qnt = w & 1;
  const uint16_t* wrQ = Wc + (size_t)(qct * 32 + l31) * 256 + half * 8;

  #pragma unroll
  for (int kk = 0; kk < 16; ++kk) {
    short8 aV = *reinterpret_cast<const short8*>(wrV + kk * 16);
    short8 b0 = ld8(&sm.xs[l31     ][kk * 16 + half * 8]);
    short8 b1 = ld8(&sm.xs[32 + l31][kk * 16 + half * 8]);
    accV0 = __builtin_amdgcn_mfma_f32_32x32x16_bf16(aV, b0, accV0, 0, 0, 0);
    accV1 = __builtin_amdgcn_mfma_f32_32x32x16_bf16(aV, b1, accV1, 0, 0, 0);
    if (w < 4) {
      short8 aQ = *reinterpret_cast<const short8*>(wrQ + kk * 16);
      accQ = __builtin_amdgcn_mfma_f32_32x32x16_bf16(aQ, qnt ? b1 : b0, accQ, 0, 0, 0);
    }
  }
  __syncthreads();   // xs reads done -> epilogue buffers may overwrite

  // ---- Q/K epilogue (waves 0-3): D -> qs[n][c0..63] with bias ----
  if (w < 4) {
    #pragma unroll
    for (int q4 = 0; q4 < 4; ++q4) {
      int cb = qct * 32 + q4 * 8 + half * 4;
      const float* bb = bc + cb;
      uint2 pk2;
      pk2.x = pkbf(accQ[q4 * 4 + 0] + bb[0], accQ[q4 * 4 + 1] + bb[1]);
      pk2.y = pkbf(accQ[q4 * 4 + 2] + bb[2], accQ[q4 * 4 + 3] + bb[3]);
      *reinterpret_cast<uint2*>(&sm.e.qs[qnt * 32 + l31][cb]) = pk2;
    }
  }
  // ---- V epilogue part 1: D -> vs[c'][n] with bias (c' = c-64) ----
  #pragma unroll
  for (int reg = 0; reg < 16; ++reg) {
    int cl = (reg & 3) + 8 * (reg >> 2) + 4 * half;
    int cp = w * 32 + cl;
    float bias = bc[64 + cp];
    sm.e.vs[cp][l31     ] = f2bfr(accV0[reg] + bias);
    sm.e.vs[cp][32 + l31] = f2bfr(accV1[reg] + bias);
  }
  __syncthreads();

  // ---- Qw/Kw stores (row n, 64B each) ----
  if (tid < 256) {
    int n = tid >> 2, sub = tid & 3;
    const uint16_t* row = sm.e.qs[n];
    uint4 d0 = *reinterpret_cast<const uint4*>(&row[sub * 16]);
    uint4 d1 = *reinterpret_cast<const uint4*>(&row[sub * 16 + 8]);
    size_t nn = (size_t)b * N_ + n0 + n;
    if (sub < 2) {
      uint4* dst = reinterpret_cast<uint4*>(Qw + nn * 32 + sub * 16);
      dst[0] = d0; dst[1] = d1;
    } else {
      uint4* dst = reinterpret_cast<uint4*>(Kw + nn * 32 + (sub - 2) * 16);
      dst[0] = d0; dst[1] = d1;
    }
  }
  // ---- V epilogue part 2: vs -> swizzled Vw, 4x dwordx4 per thread ----
  const size_t blk = ((size_t)b * 64 + tile) * 4;
  #pragma unroll
  for (int i = 0; i < 4; ++i) {
    int s = i * 512 + tid;                // lane-major in c' -> coalesced
    int cp = s & 255, rem = s >> 8;       // rem: 0..7
    int ks = rem >> 1, h2 = rem & 1;
    uint4 d = *reinterpret_cast<const uint4*>(&sm.e.vs[cp][ks * 16 + h2 * 8]);
    size_t vaddr = (blk + (cp >> 6)) * 4096
                 + (size_t)(ks * 1024 + ((cp >> 5) & 1) * 512 + h2 * 256
                            + (cp & 31) * 8);
    *reinterpret_cast<uint4*>(Vw + vaddr) = d;
  }
}

// ---------------------------------------------------------------------------
// Kernel 2: MFMA flash attention. 512 thr, grid 512, XCD-pinned.
// ROUND-11 BODY VERBATIM (passing, 97.5us; R12's 32-row/occupancy variant
// regressed to 121us -> occupancy exonerated; this is the measured optimum).
// ---------------------------------------------------------------------------
__global__ __launch_bounds__(512, 4) void attn_mfma(
    const uint16_t* __restrict__ Qw, const uint16_t* __restrict__ Kw,
    const uint16_t* __restrict__ Vw, const float* __restrict__ x,
    const float* __restrict__ gamma, float* __restrict__ out)
{
  __shared__ __align__(16) union Smem {
    uint16_t Ps[2][64 * 76];      // 19456 B, rows 152B (38 dw == 6 mod 32)
    float Os[128 * 69];           // 35328 B, stride 69 == 5 mod 32
  } sm;
  __shared__ float Ls[64];

  const int b = blockIdx.x & 7;         // XCD pin (matches qkv)
  const int m0 = (blockIdx.x >> 3) * 64;
  const int tid = threadIdx.x;
  const int w = tid >> 6, lane = tid & 63;
  const int l15 = lane & 15, q = lane >> 4;
  const int l31 = lane & 31, half = lane >> 5;
  const int nb = w & 3, mbp = (w >> 2) * 2;     // S assignment

  const uint16_t* Kb = Kw + (size_t)b * N_ * 32 + (size_t)(nb * 16 + l15) * 32 + q * 8;
  const short8 qf0 = *reinterpret_cast<const short8*>(
      Qw + ((size_t)b * N_ + m0 + (mbp    ) * 16 + l15) * 32 + q * 8);
  const short8 qf1 = *reinterpret_cast<const short8*>(
      Qw + ((size_t)b * N_ + m0 + (mbp + 1) * 16 + l15) * 32 + q * 8);
  // swizzled V: lane offset within (b, tile, cg) 4096-elem block
  const uint16_t* Vb = Vw + ((size_t)b * 256 + (w >> 1)) * 4096
                     + (w & 1) * 512 + half * 256 + l31 * 8;

  floatx16 O[2];
  #pragma unroll
  for (int i = 0; i < 16; ++i) { O[0][i] = 0.f; O[1][i] = 0.f; }
  float rs0 = 0.f, rs1 = 0.f;
  const float4v zero4 = (float4v){0.f, 0.f, 0.f, 0.f};
  if (tid < 64) Ls[tid] = 0.f;

  // ---- prolog: S[0] -> Ps[0]; preload vc = V(0), kc = K(1) ----
  short8 vc[4];
  #pragma unroll
  for (int ks = 0; ks < 4; ++ks)
    vc[ks] = *reinterpret_cast<const short8*>(Vb + ks * 1024);
  short8 kc = *reinterpret_cast<const short8*>(Kb + (size_t)64 * 32);
  {
    short8 kf = *reinterpret_cast<const short8*>(Kb);
    float4v s0 = __builtin_amdgcn_mfma_f32_16x16x32_bf16(kf, qf0, zero4, 0, 0, 0);
    float4v s1 = __builtin_amdgcn_mfma_f32_16x16x32_bf16(kf, qf1, zero4, 0, 0, 0);
    float p0 = ex2(s0.x), p1 = ex2(s0.y), p2 = ex2(s0.z), p3 = ex2(s0.w);
    rs0 += (p0 + p1) + (p2 + p3);
    uint2 pw; pw.x = pkbf(p0, p1); pw.y = pkbf(p2, p3);
    *reinterpret_cast<uint2*>(&sm.Ps[0][((mbp)*16 + l15) * 76 + nb * 16 + q * 4]) = pw;
    float r0 = ex2(s1.x), r1 = ex2(s1.y), r2 = ex2(s1.z), r3 = ex2(s1.w);
    rs1 += (r0 + r1) + (r2 + r3);
    uint2 rw; rw.x = pkbf(r0, r1); rw.y = pkbf(r2, r3);
    *reinterpret_cast<uint2*>(&sm.Ps[0][((mbp + 1)*16 + l15) * 76 + nb * 16 + q * 4]) = rw;
  }
  __syncthreads();

  for (int t = 0; t < 64; ++t) {
    const int buf = t & 1;

    // issue NEXT-iter loads (consumed next iteration -> full-iter latency cover)
    short8 vn[4];
    if (t < 63) {
      const uint16_t* vt = Vb + (size_t)(t + 1) * 16384;
      #pragma unroll
      for (int ks = 0; ks < 4; ++ks)
        vn[ks] = *reinterpret_cast<const short8*>(vt + ks * 1024);
    }
    short8 kn;
    if (t < 62)
      kn = *reinterpret_cast<const short8*>(Kb + (size_t)(t + 2) * 64 * 32);

    // ---- S[t+1] -> Ps[buf^1] (kc loaded last iter, already in registers) ----
    if (t < 63) {
      float4v s0 = __builtin_amdgcn_mfma_f32_16x16x32_bf16(kc, qf0, zero4, 0, 0, 0);
      float4v s1 = __builtin_amdgcn_mfma_f32_16x16x32_bf16(kc, qf1, zero4, 0, 0, 0);
      float p0 = ex2(s0.x), p1 = ex2(s0.y), p2 = ex2(s0.z), p3 = ex2(s0.w);
      rs0 += (p0 + p1) + (p2 + p3);
      uint2 pw; pw.x = pkbf(p0, p1); pw.y = pkbf(p2, p3);
      *reinterpret_cast<uint2*>(&sm.Ps[buf ^ 1][((mbp)*16 + l15) * 76 + nb * 16 + q * 4]) = pw;
      float r0 = ex2(s1.x), r1 = ex2(s1.y), r2 = ex2(s1.z), r3 = ex2(s1.w);
      rs1 += (r0 + r1) + (r2 + r3);
      uint2 rw; rw.x = pkbf(r0, r1); rw.y = pkbf(r2, r3);
      *reinterpret_cast<uint2*>(&sm.Ps[buf ^ 1][((mbp + 1)*16 + l15) * 76 + nb * 16 + q * 4]) = rw;
    }

    // ---- PV[t]: A = Ps[buf] via 2xb64 (both m-halves), B = vc (registers) ----
    #pragma unroll
    for (int ks = 0; ks < 4; ++ks) {
      short8 pa0 = ld8(&sm.Ps[buf][(l31     ) * 76 + ks * 16 + half * 8]);
      short8 pa1 = ld8(&sm.Ps[buf][(32 + l31) * 76 + ks * 16 + half * 8]);
      O[0] = __builtin_amdgcn_mfma_f32_32x32x16_bf16(pa0, vc[ks], O[0], 0, 0, 0);
      O[1] = __builtin_amdgcn_mfma_f32_32x32x16_bf16(pa1, vc[ks], O[1], 0, 0, 0);
    }
    __syncthreads();

    // rotate register prefetch buffers
    if (t < 63) {
      #pragma unroll
      for (int ks = 0; ks < 4; ++ks) vc[ks] = vn[ks];
    }
    if (t < 62) kc = kn;
  }

  // ---- row sums -> Ls = gamma / rowsum ----
  rs0 += __shfl_xor(rs0, 16); rs0 += __shfl_xor(rs0, 32);
  rs1 += __shfl_xor(rs1, 16); rs1 += __shfl_xor(rs1, 32);
  if (q == 0) {
    atomicAdd(&Ls[(mbp    ) * 16 + l15], rs0);
    atomicAdd(&Ls[(mbp + 1) * 16 + l15], rs1);
  }
  __syncthreads();
  if (tid < 64) Ls[tid] = gamma[0] / Ls[tid];
  __syncthreads();   // Ls ready; all Ps reads done -> Os may overwrite

  // ---- epilogue: O (32x32 D layout) -> Os transpose -> coalesced stores ----
  #pragma unroll
  for (int chunk = 0; chunk < 2; ++chunk) {
    if ((w >> 2) == chunk) {
      int cl = (w & 3) * 32 + l31;
      #pragma unroll
      for (int h = 0; h < 2; ++h)
        #pragma unroll
        for (int reg = 0; reg < 16; ++reg) {
          int m = h * 32 + (reg & 3) + 8 * (reg >> 2) + 4 * half;
          sm.Os[cl * 69 + m] = O[h][reg] * Ls[m];
        }
    }
    __syncthreads();
    {
      int cl = tid >> 2, msub = tid & 3;
      int c = chunk * 128 + cl;
      size_t idx = ((size_t)b * C_ + c) * N_ + m0 + msub * 16;
      const float* os = &sm.Os[cl * 69 + msub * 16];
      #pragma unroll
      for (int i = 0; i < 4; ++i) {
        float4 xv = *reinterpret_cast<const float4*>(x + idx + i * 4);
        float4 ov;
        ov.x = os[i * 4 + 0] + xv.x;
        ov.y = os[i * 4 + 1] + xv.y;
        ov.z = os[i * 4 + 2] + xv.z;
        ov.w = os[i * 4 + 3] + xv.w;
        *reinterpret_cast<float4*>(out + idx + i * 4) = ov;
      }
    }
    __syncthreads();
  }
}

extern "C" void kernel_launch(void* const* d_in, const int* in_sizes, int n_in,
                              void* d_out, int out_size, void* d_ws, size_t ws_size,
                              hipStream_t stream) {
  const float* x     = (const float*)d_in[0];
  const float* Wq    = (const float*)d_in[1];
  const float* bq    = (const float*)d_in[2];
  const float* Wk    = (const float*)d_in[3];
  const float* bk    = (const float*)d_in[4];
  const float* Wv    = (const float*)d_in[5];
  const float* bv    = (const float*)d_in[6];
  const float* gamma = (const float*)d_in[7];
  float* out = (float*)d_out;

  // ws: Qw bf16 2MB | Kw bf16 2MB | Vw bf16 16MB (swizzled) | Wc | bc
  uint16_t* Qw = (uint16_t*)d_ws;
  uint16_t* Kw = Qw + (size_t)B_ * N_ * 32;
  uint16_t* Vw = Kw + (size_t)B_ * N_ * 32;
  uint16_t* Wc = Vw + (size_t)B_ * C_ * N_;
  float*    bc = (float*)(Wc + 320 * 256);

  wconv_kernel<<<80, 256, 0, stream>>>(Wq, bq, Wk, bk, Wv, bv, Wc, bc);
  qkv_mfma<<<512, 512, 0, stream>>>(x, Wc, bc, Qw, Kw, Vw);
  attn_mfma<<<512, 512, 0, stream>>>(Qw, Kw, Vw, x, gamma, out);
}